// Round 10
// baseline (126.349 us; speedup 1.0000x reference)
//
#include <hip/hip_runtime.h>

#define NBATCH 256

typedef __attribute__((ext_vector_type(8))) short bf16x8;
typedef __attribute__((ext_vector_type(4))) float f32x4;

__device__ __forceinline__ unsigned short f2b(float f) {
    unsigned u = __float_as_uint(f);
    u = (u + 0x7fffu + ((u >> 16) & 1u)) >> 16;
    return (unsigned short)u;
}
__device__ __forceinline__ void async16(const void* g, void* l) {
    __builtin_amdgcn_global_load_lds((const __attribute__((address_space(1))) unsigned int*)g,
                                     (__attribute__((address_space(3))) unsigned int*)l, 16, 0, 0);
}

// ---------------- fused prep kernel (x4 vectorized, unchanged tiling) ----------------
// blocks [0,512): W0 ; [512,1536): W1 ; [1536,2560): W2 ; [2560,3584): x
// W tiling: granule per (rg, kstep): [kseg(4)][l15(16)][j(8)]; kstep = f*NCS + cs.
// x0fp: fold-scale pack [b][f][l15][nt]  (elem (e&15)*4 + (e>>4))
__global__ void prep_all(const float* __restrict__ x,
                         const float* __restrict__ W0,
                         const float* __restrict__ W1,
                         const float* __restrict__ W2,
                         unsigned short* __restrict__ x0t,
                         unsigned short* __restrict__ x0fp,
                         unsigned short* __restrict__ Wp0,
                         unsigned short* __restrict__ Wp1,
                         unsigned short* __restrict__ Wp2)
{
    const int bid = blockIdx.x, tid = threadIdx.x;
    if (bid < 2560) {
        const float* W; unsigned short* Wp; int CLOG, KLOG, lbid;
        if (bid < 512)       { W = W0; Wp = Wp0; CLOG = 6; KLOG = 12; lbid = bid; }
        else if (bid < 1536) { W = W1; Wp = Wp1; CLOG = 7; KLOG = 13; lbid = bid - 512; }
        else                 { W = W2; Wp = Wp2; CLOG = 7; KLOG = 13; lbid = bid - 1536; }
        const int base = (lbid * 256 + tid) * 4;   // 4 consecutive k, same o
        int o = base >> KLOG, k = base & ((1 << KLOG) - 1);
        int f = k >> CLOG, c = k & ((1 << CLOG) - 1);
        int rg = o >> 4, l15 = o & 15;
        int cs = c >> 5, kseg = (c >> 3) & 3, j = c & 7;   // j aligned to 4
        int NCS = 1 << (CLOG - 5);
        int NK = 64 * NCS;
        int kstep = f * NCS + cs;
        size_t dst = (((size_t)rg * NK + kstep) * 64 + kseg * 16 + l15) * 8 + j;
        const float4 wv = *(const float4*)(W + base);
        *(ushort4*)(Wp + dst) = make_ushort4(f2b(wv.x), f2b(wv.y), f2b(wv.z), f2b(wv.w));
    } else {
        const int base = ((bid - 2560) * 256 + tid) * 4;   // 4 consecutive e
        int b = base >> 12, r = base & 4095, f = r >> 6, e0 = r & 63;
        const float4 xv = *(const float4*)(x + base);
        ushort4 v = make_ushort4(f2b(xv.x), f2b(xv.y), f2b(xv.z), f2b(xv.w));
        unsigned short* xp = x0fp + b * 4096 + f * 64;
        const int hi = e0 >> 4;                            // same for e0..e0+3
        xp[((e0 + 0) & 15) * 4 + hi] = v.x;                // [l15][nt] pack
        xp[((e0 + 1) & 15) * 4 + hi] = v.y;
        xp[((e0 + 2) & 15) * 4 + hi] = v.z;
        xp[((e0 + 3) & 15) * 4 + hi] = v.w;
        x0t[b * 4096 + (e0 + 0) * 64 + f] = v.x;           // [b][e][f]
        x0t[b * 4096 + (e0 + 1) * 64 + f] = v.y;
        x0t[b * 4096 + (e0 + 2) * 64 + f] = v.z;
        x0t[b * 4096 + (e0 + 3) * 64 + f] = v.w;
    }
}

// ---------------- per-layer GEMM kernel ----------------
// grid 512 = 8 rg x 64 sgg; 512 thr, 8 waves: sample p = w&3, kg = w>>2 (c-half).
// A: global->LDS, 3-buffer x 8KB chunks, counted vmcnt(1) + raw s_barrier
//    (one barrier/chunk, loads 2 chunks in flight, NO vmcnt(0) drain mid-loop).
// B: VGPR-resident, asm-pinned. Scales: batch ds_read_b64 per chunk.
template <int CL, bool LAST>
__global__ __launch_bounds__(512, 2) void layer_k(
    const unsigned short* __restrict__ Wp,    // pre-tiled A, rg-sliced
    const unsigned short* __restrict__ Bsrc,  // [b][e][c] rows of CL*2 bytes
    const unsigned short* __restrict__ x0fp,  // [b][f][l15][nt] packed scales
    const float* __restrict__ Wa_l,
    unsigned short* __restrict__ xknext,      // [b][e][o] rows of 256B
    float* __restrict__ ybuf)                 // [256][8] this layer
{
    constexpr int NCS  = CL / 32;             // cs granules per field (2 or 4)
    constexpr int NCS2 = NCS / 2;             // per-wave (1 or 2)
    constexpr int NK   = 64 * NCS;            // granules in rg slice
    constexpr int NCH  = NK / 8;              // 8-granule chunks (16 or 32)
    constexpr int FPC  = 8 / NCS;             // fields per chunk (4 or 2)
    __shared__ char sm[57344];
    char* smA = sm;            // 3 x 8 KB A chunk buffers (reduce reuses)
    char* smX = sm + 24576;    // 4 x 8 KB per-sample packed scales

    const int bid = blockIdx.x, tid = threadIdx.x;
    const int rg = bid & 7, sgg = bid >> 3;
    const int lane = tid & 63, w = tid >> 6;
    const int p = w & 3, kg = w >> 2;
    const int s = sgg * 4 + p;
    const int l15 = lane & 15, kseg = lane >> 4;

    // stage 4 samples' packed scales (8 KB each)
#pragma unroll
    for (int q = 0; q < 4; ++q)
        async16((const char*)x0fp + (size_t)(sgg * 4 + q) * 8192 + w * 1024 + lane * 16,
                smX + q * 8192 + w * 1024);

    const char* Ab = (const char*)Wp + (size_t)rg * NK * 1024;
    auto stage = [&](int ch, int buf) {
        async16(Ab + ((size_t)ch * 8 + w) * 1024 + lane * 16,
                smA + buf * 8192 + w * 1024);        // 1 load/wave/chunk
    };
    stage(0, 0);
    stage(1, 1);

    // B granules for this wave's c-half: load once, VGPR-resident
    bf16x8 bq[NCS2][4];
    {
        const char* Bb = (const char*)Bsrc + (size_t)s * (CL * 128) + kseg * 16;
#pragma unroll
        for (int i = 0; i < NCS2; ++i)
#pragma unroll
            for (int nt = 0; nt < 4; ++nt)
                bq[i][nt] = *(const bf16x8*)(Bb + (nt * 16 + l15) * (CL * 2)
                                             + (kg * NCS2 + i) * 64);
    }

    const unsigned short* XS = (const unsigned short*)(smX + p * 8192);
    const f32x4 ZERO = {0.f, 0.f, 0.f, 0.f};
    f32x4 acc[4], accf[4];
#pragma unroll
    for (int nt = 0; nt < 4; ++nt) acc[nt] = ZERO;

    int cur = 0;
    for (int ch = 0; ch < NCH; ++ch) {
        // counted wait: own chunk-ch load done, chunk ch+1 still in flight
        if (ch == NCH - 1) asm volatile("s_waitcnt vmcnt(0)\ns_barrier" ::: "memory");
        else               asm volatile("s_waitcnt vmcnt(1)\ns_barrier" ::: "memory");
        if (ch + 2 < NCH) stage(ch + 2, cur == 0 ? 2 : (cur == 1 ? 0 : 1));
        // pin bq (prevents the compiler sinking B loads into the loop)
#pragma unroll
        for (int i = 0; i < NCS2; ++i)
            asm volatile("" :: "v"(bq[i][0]), "v"(bq[i][1]), "v"(bq[i][2]), "v"(bq[i][3]));
        const char* Abuf = smA + cur * 8192 + lane * 16;
        // batch-read this chunk's fold scales (independent ds_read_b64s)
        uint2 sp[FPC];
#pragma unroll
        for (int fi = 0; fi < FPC; ++fi)
            sp[fi] = *(const uint2*)(XS + (ch * FPC + fi) * 64 + l15 * 4);
#pragma unroll
        for (int fi = 0; fi < FPC; ++fi) {
            const float sv0 = __uint_as_float(sp[fi].x << 16);
            const float sv1 = __uint_as_float(sp[fi].x & 0xffff0000u);
            const float sv2 = __uint_as_float(sp[fi].y << 16);
            const float sv3 = __uint_as_float(sp[fi].y & 0xffff0000u);
            bf16x8 a[NCS2];
#pragma unroll
            for (int i = 0; i < NCS2; ++i)
                a[i] = *(const bf16x8*)(Abuf + (fi * NCS + kg * NCS2 + i) * 1024);
#pragma unroll
            for (int i = 0; i < NCS2; ++i)
#pragma unroll
                for (int nt = 0; nt < 4; ++nt)
                    accf[nt] = __builtin_amdgcn_mfma_f32_16x16x32_bf16(
                        a[i], bq[i][nt], (i == 0) ? ZERO : accf[nt], 0, 0, 0);
            acc[0] += accf[0] * f32x4{sv0, sv0, sv0, sv0};
            acc[1] += accf[1] * f32x4{sv1, sv1, sv1, sv1};
            acc[2] += accf[2] * f32x4{sv2, sv2, sv2, sv2};
            acc[3] += accf[3] * f32x4{sv3, sv3, sv3, sv3};
        }
        cur = (cur == 2) ? 0 : cur + 1;
    }
    __syncthreads();   // full drain before LDS reuse

    // ---- cross-kg reduction (reuse A region, 16KB needed <= 24KB) ----
    if (kg == 1) {
#pragma unroll
        for (int nt = 0; nt < 4; ++nt)
            *(f32x4*)(smA + p * 4096 + lane * 64 + nt * 16) = acc[nt];
    }
    __syncthreads();
    if (kg == 0) {
#pragma unroll
        for (int nt = 0; nt < 4; ++nt)
            acc[nt] += *(const f32x4*)(smA + p * 4096 + lane * 64 + nt * 16);

        // epilogue: relu, y-partial, xknext write (validated mapping)
        const float4 wa = *(const float4*)(Wa_l + rg * 16 + kseg * 4);
        float ypart = 0.f;
#pragma unroll
        for (int nt = 0; nt < 4; ++nt) {
            f32x4 v = acc[nt];
            v.x = fmaxf(v.x, 0.f); v.y = fmaxf(v.y, 0.f);
            v.z = fmaxf(v.z, 0.f); v.w = fmaxf(v.w, 0.f);
            ypart = fmaf(wa.x, v.x, ypart);
            ypart = fmaf(wa.y, v.y, ypart);
            ypart = fmaf(wa.z, v.z, ypart);
            ypart = fmaf(wa.w, v.w, ypart);
            if (!LAST) {
                unsigned lo = (unsigned)f2b(v.x) | ((unsigned)f2b(v.y) << 16);
                unsigned hi = (unsigned)f2b(v.z) | ((unsigned)f2b(v.w) << 16);
                *(uint2*)((char*)xknext + (size_t)s * 16384 + (nt * 16 + l15) * 256
                          + (rg * 16 + kseg * 4) * 2) = make_uint2(lo, hi);
            }
        }
#pragma unroll
        for (int off = 32; off >= 1; off >>= 1)
            ypart += __shfl_down(ypart, off, 64);
        if (lane == 0) ybuf[s * 8 + rg] = ypart;
    }
}

__global__ void finalize_k(const float* __restrict__ ybuf, float* __restrict__ y) {
    const int b = threadIdx.x;
    float sum = 0.f;
#pragma unroll
    for (int l = 0; l < 3; ++l)
#pragma unroll
        for (int r = 0; r < 8; ++r)
            sum += ybuf[l * 2048 + b * 8 + r];
    y[b] = sum;
}

extern "C" void kernel_launch(void* const* d_in, const int* in_sizes, int n_in,
                              void* d_out, int out_size, void* d_ws, size_t ws_size,
                              hipStream_t stream) {
    const float* x  = (const float*)d_in[0];
    const float* W0 = (const float*)d_in[1];
    const float* W1 = (const float*)d_in[2];
    const float* W2 = (const float*)d_in[3];
    const float* Wa = (const float*)d_in[4];
    float* y = (float*)d_out;

    char* ws = (char*)d_ws;
    unsigned short* Wp0  = (unsigned short*)(ws + 0x000000);   // 1MB (+pad)
    unsigned short* Wp1  = (unsigned short*)(ws + 0x110000);   // 2MB (+pad)
    unsigned short* Wp2  = (unsigned short*)(ws + 0x320000);   // 2MB (+pad)
    unsigned short* x0t  = (unsigned short*)(ws + 0x530000);   // 2MB
    unsigned short* x0fp = (unsigned short*)(ws + 0x730000);   // 2MB
    unsigned short* xkA  = (unsigned short*)(ws + 0x930000);   // 4MB
    unsigned short* xkB  = (unsigned short*)(ws + 0xD30000);   // 4MB
    float*          ybuf = (float*)(ws + 0x1130000);           // 24KB

    hipLaunchKernelGGL(prep_all, dim3(3584), dim3(256), 0, stream,
                       x, W0, W1, W2, x0t, x0fp, Wp0, Wp1, Wp2);

    hipLaunchKernelGGL((layer_k<64, false>), dim3(512), dim3(512), 0, stream,
                       Wp0, x0t, x0fp, Wa + 0, xkA, ybuf + 0);
    hipLaunchKernelGGL((layer_k<128, false>), dim3(512), dim3(512), 0, stream,
                       Wp1, xkA, x0fp, Wa + 128, xkB, ybuf + 2048);
    hipLaunchKernelGGL((layer_k<128, true>), dim3(512), dim3(512), 0, stream,
                       Wp2, xkB, x0fp, Wa + 256, xkA, ybuf + 4096);

    hipLaunchKernelGGL(finalize_k, dim3(1), dim3(256), 0, stream, ybuf, y);
}

// Round 11
// 113.769 us; speedup vs baseline: 1.1106x; 1.1106x over previous
//
#include <hip/hip_runtime.h>

#define NBATCH 256

typedef __attribute__((ext_vector_type(8))) short bf16x8;
typedef __attribute__((ext_vector_type(4))) float f32x4;

__device__ __forceinline__ unsigned short f2b(float f) {
    unsigned u = __float_as_uint(f);
    u = (u + 0x7fffu + ((u >> 16) & 1u)) >> 16;
    return (unsigned short)u;
}
__device__ __forceinline__ void async16(const void* g, void* l) {
    __builtin_amdgcn_global_load_lds((const __attribute__((address_space(1))) unsigned int*)g,
                                     (__attribute__((address_space(3))) unsigned int*)l, 16, 0, 0);
}

// ---------------- fused prep kernel (unchanged from R9) ----------------
__global__ void prep_all(const float* __restrict__ x,
                         const float* __restrict__ W0,
                         const float* __restrict__ W1,
                         const float* __restrict__ W2,
                         unsigned short* __restrict__ x0t,
                         unsigned short* __restrict__ x0fp,
                         unsigned short* __restrict__ Wp0,
                         unsigned short* __restrict__ Wp1,
                         unsigned short* __restrict__ Wp2)
{
    const int bid = blockIdx.x, tid = threadIdx.x;
    if (bid < 2560) {
        const float* W; unsigned short* Wp; int CLOG, KLOG, lbid;
        if (bid < 512)       { W = W0; Wp = Wp0; CLOG = 6; KLOG = 12; lbid = bid; }
        else if (bid < 1536) { W = W1; Wp = Wp1; CLOG = 7; KLOG = 13; lbid = bid - 512; }
        else                 { W = W2; Wp = Wp2; CLOG = 7; KLOG = 13; lbid = bid - 1536; }
        const int base = (lbid * 256 + tid) * 4;   // 4 consecutive k, same o
        int o = base >> KLOG, k = base & ((1 << KLOG) - 1);
        int f = k >> CLOG, c = k & ((1 << CLOG) - 1);
        int rg = o >> 4, l15 = o & 15;
        int cs = c >> 5, kseg = (c >> 3) & 3, j = c & 7;   // j aligned to 4
        int NCS = 1 << (CLOG - 5);
        int NK = 64 * NCS;
        int kstep = f * NCS + cs;
        size_t dst = (((size_t)rg * NK + kstep) * 64 + kseg * 16 + l15) * 8 + j;
        const float4 wv = *(const float4*)(W + base);
        *(ushort4*)(Wp + dst) = make_ushort4(f2b(wv.x), f2b(wv.y), f2b(wv.z), f2b(wv.w));
    } else {
        const int base = ((bid - 2560) * 256 + tid) * 4;   // 4 consecutive e
        int b = base >> 12, r = base & 4095, f = r >> 6, e0 = r & 63;
        const float4 xv = *(const float4*)(x + base);
        ushort4 v = make_ushort4(f2b(xv.x), f2b(xv.y), f2b(xv.z), f2b(xv.w));
        unsigned short* xp = x0fp + b * 4096 + f * 64;
        const int hi = e0 >> 4;                            // same for e0..e0+3
        xp[((e0 + 0) & 15) * 4 + hi] = v.x;                // [l15][nt] pack
        xp[((e0 + 1) & 15) * 4 + hi] = v.y;
        xp[((e0 + 2) & 15) * 4 + hi] = v.z;
        xp[((e0 + 3) & 15) * 4 + hi] = v.w;
        x0t[b * 4096 + (e0 + 0) * 64 + f] = v.x;           // [b][e][f]
        x0t[b * 4096 + (e0 + 1) * 64 + f] = v.y;
        x0t[b * 4096 + (e0 + 2) * 64 + f] = v.z;
        x0t[b * 4096 + (e0 + 3) * 64 + f] = v.w;
    }
}

// ---------------- per-layer GEMM kernel ----------------
// grid 512 = 8 rg x 64 sgg; 512 thr, 8 waves: sample p = w&3, kg = w>>2 (c-half).
// A: global->LDS 16KB chunks, 2 buffers, 1 __syncthreads/chunk (R9 staging).
// Field-level software pipeline: accfA/accfB double-buffer (fold of field f-1
// issues after MFMAs of field f), A-regs aA/aB prefetched 2 fields ahead,
// chunk-batched scale reads. B VGPR-resident, asm-pinned per chunk.
template <int CL, bool LAST>
__global__ __launch_bounds__(512, 2) void layer_k(
    const unsigned short* __restrict__ Wp,    // pre-tiled A, rg-sliced
    const unsigned short* __restrict__ Bsrc,  // [b][e][c] rows of CL*2 bytes
    const unsigned short* __restrict__ x0fp,  // [b][f][l15][nt] packed scales
    const float* __restrict__ Wa_l,
    unsigned short* __restrict__ xknext,      // [b][e][o] rows of 256B
    float* __restrict__ ybuf)                 // [256][8] this layer
{
    constexpr int NCS  = CL / 32;             // cs granules per field (2 or 4)
    constexpr int NCS2 = NCS / 2;             // per-wave (1 or 2)
    constexpr int NK   = 64 * NCS;            // granules in rg slice
    constexpr int NCH  = NK / 16;             // 16-granule (16KB) chunks (8/16)
    constexpr int FPC  = 16 / NCS;            // fields per chunk (8 or 4)
    __shared__ char sm[65536];
    char* smA = sm;            // 2 x 16 KB A chunk buffers (reduce reuses)
    char* smX = sm + 32768;    // 4 x 8 KB per-sample packed scales

    const int bid = blockIdx.x, tid = threadIdx.x;
    const int rg = bid & 7, sgg = bid >> 3;
    const int lane = tid & 63, w = tid >> 6;
    const int p = w & 3, kg = w >> 2;
    const int s = sgg * 4 + p;
    const int l15 = lane & 15, kseg = lane >> 4;

    // stage 4 samples' packed scales (8 KB each)
#pragma unroll
    for (int q = 0; q < 4; ++q)
        async16((const char*)x0fp + (size_t)(sgg * 4 + q) * 8192 + w * 1024 + lane * 16,
                smX + q * 8192 + w * 1024);

    const char* Ab = (const char*)Wp + (size_t)rg * NK * 1024;
    auto stage = [&](int ch, int buf) {
        const char* src = Ab + ((size_t)ch * 16 + w * 2) * 1024 + lane * 16;
        char* dst = smA + buf * 16384 + w * 2048;   // wave-uniform dst
        async16(src, dst);
        async16(src + 1024, dst + 1024);
    };
    stage(0, 0);

    // B granules for this wave's c-half: load once, VGPR-resident
    bf16x8 bq[NCS2][4];
    {
        const char* Bb = (const char*)Bsrc + (size_t)s * (CL * 128) + kseg * 16;
#pragma unroll
        for (int i = 0; i < NCS2; ++i)
#pragma unroll
            for (int nt = 0; nt < 4; ++nt)
                bq[i][nt] = *(const bf16x8*)(Bb + (nt * 16 + l15) * (CL * 2)
                                             + (kg * NCS2 + i) * 64);
    }
    __syncthreads();   // scales + chunk0 complete

    const unsigned short* XS = (const unsigned short*)(smX + p * 8192);
    const f32x4 ZERO = {0.f, 0.f, 0.f, 0.f};
    f32x4 acc[4];
#pragma unroll
    for (int nt = 0; nt < 4; ++nt) acc[nt] = ZERO;
    f32x4 accfA[4], accfB[4];
    bf16x8 aA[NCS2], aB[NCS2];

#define LDA(DST, FI) { _Pragma("unroll") for (int i_ = 0; i_ < NCS2; ++i_) \
    DST[i_] = *(const bf16x8*)(Abuf + ((FI) * NCS + kg * NCS2 + i_) * 1024); }
#define MFMA_STEP(A, F) { _Pragma("unroll") for (int i_ = 0; i_ < NCS2; ++i_) \
    _Pragma("unroll") for (int nt_ = 0; nt_ < 4; ++nt_) \
        F[nt_] = __builtin_amdgcn_mfma_f32_16x16x32_bf16( \
            A[i_], bq[i_][nt_], (i_ == 0) ? ZERO : F[nt_], 0, 0, 0); }
#define FOLD(F, SP) { \
    const float sv0_ = __uint_as_float((SP).x << 16); \
    const float sv1_ = __uint_as_float((SP).x & 0xffff0000u); \
    const float sv2_ = __uint_as_float((SP).y << 16); \
    const float sv3_ = __uint_as_float((SP).y & 0xffff0000u); \
    acc[0] += F[0] * f32x4{sv0_, sv0_, sv0_, sv0_}; \
    acc[1] += F[1] * f32x4{sv1_, sv1_, sv1_, sv1_}; \
    acc[2] += F[2] * f32x4{sv2_, sv2_, sv2_, sv2_}; \
    acc[3] += F[3] * f32x4{sv3_, sv3_, sv3_, sv3_}; }

    for (int ch = 0; ch < NCH; ++ch) {
        const int cur = ch & 1;
        if (ch + 1 < NCH) stage(ch + 1, cur ^ 1);
        // pin bq (prevents the compiler sinking B loads into the loop)
#pragma unroll
        for (int i = 0; i < NCS2; ++i)
            asm volatile("" :: "v"(bq[i][0]), "v"(bq[i][1]), "v"(bq[i][2]), "v"(bq[i][3]));
        const char* Abuf = smA + cur * 16384 + lane * 16;
        // batch this chunk's fold scales (independent ds_read_b64s)
        uint2 sp[FPC];
#pragma unroll
        for (int fi = 0; fi < FPC; ++fi)
            sp[fi] = *(const uint2*)(XS + (ch * FPC + fi) * 64 + l15 * 4);
        // prologue: A for fields 0,1
        LDA(aA, 0);
        LDA(aB, 1);
        // pipelined field pairs: MFMA(f) ; prefetch(f+2) ; fold(f-1)
#pragma unroll
        for (int q = 0; q < FPC / 2; ++q) {
            MFMA_STEP(aA, accfA);                    // even field 2q
            if (2 * q + 2 < FPC) LDA(aA, 2 * q + 2);
            if (q > 0) FOLD(accfB, sp[2 * q - 1]);   // fold odd field of prev pair
            MFMA_STEP(aB, accfB);                    // odd field 2q+1
            if (2 * q + 3 < FPC) LDA(aB, 2 * q + 3);
            FOLD(accfA, sp[2 * q]);                  // fold even field 2q
        }
        FOLD(accfB, sp[FPC - 1]);                    // tail: last odd field
        __syncthreads();
    }
#undef LDA
#undef MFMA_STEP
#undef FOLD

    // ---- cross-kg reduction (reuse A region) ----
    if (kg == 1) {
#pragma unroll
        for (int nt = 0; nt < 4; ++nt)
            *(f32x4*)(smA + p * 4096 + lane * 64 + nt * 16) = acc[nt];
    }
    __syncthreads();
    if (kg == 0) {
#pragma unroll
        for (int nt = 0; nt < 4; ++nt)
            acc[nt] += *(const f32x4*)(smA + p * 4096 + lane * 64 + nt * 16);

        // epilogue: relu, y-partial, xknext write (validated mapping)
        const float4 wa = *(const float4*)(Wa_l + rg * 16 + kseg * 4);
        float ypart = 0.f;
#pragma unroll
        for (int nt = 0; nt < 4; ++nt) {
            f32x4 v = acc[nt];
            v.x = fmaxf(v.x, 0.f); v.y = fmaxf(v.y, 0.f);
            v.z = fmaxf(v.z, 0.f); v.w = fmaxf(v.w, 0.f);
            ypart = fmaf(wa.x, v.x, ypart);
            ypart = fmaf(wa.y, v.y, ypart);
            ypart = fmaf(wa.z, v.z, ypart);
            ypart = fmaf(wa.w, v.w, ypart);
            if (!LAST) {
                unsigned lo = (unsigned)f2b(v.x) | ((unsigned)f2b(v.y) << 16);
                unsigned hi = (unsigned)f2b(v.z) | ((unsigned)f2b(v.w) << 16);
                *(uint2*)((char*)xknext + (size_t)s * 16384 + (nt * 16 + l15) * 256
                          + (rg * 16 + kseg * 4) * 2) = make_uint2(lo, hi);
            }
        }
#pragma unroll
        for (int off = 32; off >= 1; off >>= 1)
            ypart += __shfl_down(ypart, off, 64);
        if (lane == 0) ybuf[s * 8 + rg] = ypart;
    }
}

__global__ void finalize_k(const float* __restrict__ ybuf, float* __restrict__ y) {
    const int b = threadIdx.x;
    float sum = 0.f;
#pragma unroll
    for (int l = 0; l < 3; ++l)
#pragma unroll
        for (int r = 0; r < 8; ++r)
            sum += ybuf[l * 2048 + b * 8 + r];
    y[b] = sum;
}

extern "C" void kernel_launch(void* const* d_in, const int* in_sizes, int n_in,
                              void* d_out, int out_size, void* d_ws, size_t ws_size,
                              hipStream_t stream) {
    const float* x  = (const float*)d_in[0];
    const float* W0 = (const float*)d_in[1];
    const float* W1 = (const float*)d_in[2];
    const float* W2 = (const float*)d_in[3];
    const float* Wa = (const float*)d_in[4];
    float* y = (float*)d_out;

    char* ws = (char*)d_ws;
    unsigned short* Wp0  = (unsigned short*)(ws + 0x000000);   // 1MB (+pad)
    unsigned short* Wp1  = (unsigned short*)(ws + 0x110000);   // 2MB (+pad)
    unsigned short* Wp2  = (unsigned short*)(ws + 0x320000);   // 2MB (+pad)
    unsigned short* x0t  = (unsigned short*)(ws + 0x530000);   // 2MB
    unsigned short* x0fp = (unsigned short*)(ws + 0x730000);   // 2MB
    unsigned short* xkA  = (unsigned short*)(ws + 0x930000);   // 4MB
    unsigned short* xkB  = (unsigned short*)(ws + 0xD30000);   // 4MB
    float*          ybuf = (float*)(ws + 0x1130000);           // 24KB

    hipLaunchKernelGGL(prep_all, dim3(3584), dim3(256), 0, stream,
                       x, W0, W1, W2, x0t, x0fp, Wp0, Wp1, Wp2);

    hipLaunchKernelGGL((layer_k<64, false>), dim3(512), dim3(512), 0, stream,
                       Wp0, x0t, x0fp, Wa + 0, xkA, ybuf + 0);
    hipLaunchKernelGGL((layer_k<128, false>), dim3(512), dim3(512), 0, stream,
                       Wp1, xkA, x0fp, Wa + 128, xkB, ybuf + 2048);
    hipLaunchKernelGGL((layer_k<128, true>), dim3(512), dim3(512), 0, stream,
                       Wp2, xkB, x0fp, Wa + 256, xkA, ybuf + 4096);

    hipLaunchKernelGGL(finalize_k, dim3(1), dim3(256), 0, stream, ybuf, y);
}

// Round 12
// 100.508 us; speedup vs baseline: 1.2571x; 1.1319x over previous
//
#include <hip/hip_runtime.h>

#define NBATCH 256

typedef __attribute__((ext_vector_type(8))) short bf16x8;
typedef __attribute__((ext_vector_type(4))) float f32x4;

__device__ __forceinline__ unsigned short f2b(float f) {
    unsigned u = __float_as_uint(f);
    u = (u + 0x7fffu + ((u >> 16) & 1u)) >> 16;
    return (unsigned short)u;
}
__device__ __forceinline__ void async16(const void* g, void* l) {
    __builtin_amdgcn_global_load_lds((const __attribute__((address_space(1))) unsigned int*)g,
                                     (__attribute__((address_space(3))) unsigned int*)l, 16, 0, 0);
}

// ---------------- fused prep kernel (unchanged) ----------------
__global__ void prep_all(const float* __restrict__ x,
                         const float* __restrict__ W0,
                         const float* __restrict__ W1,
                         const float* __restrict__ W2,
                         unsigned short* __restrict__ x0t,
                         unsigned short* __restrict__ x0fp,
                         unsigned short* __restrict__ Wp0,
                         unsigned short* __restrict__ Wp1,
                         unsigned short* __restrict__ Wp2)
{
    const int bid = blockIdx.x, tid = threadIdx.x;
    if (bid < 2560) {
        const float* W; unsigned short* Wp; int CLOG, KLOG, lbid;
        if (bid < 512)       { W = W0; Wp = Wp0; CLOG = 6; KLOG = 12; lbid = bid; }
        else if (bid < 1536) { W = W1; Wp = Wp1; CLOG = 7; KLOG = 13; lbid = bid - 512; }
        else                 { W = W2; Wp = Wp2; CLOG = 7; KLOG = 13; lbid = bid - 1536; }
        const int base = (lbid * 256 + tid) * 4;   // 4 consecutive k, same o
        int o = base >> KLOG, k = base & ((1 << KLOG) - 1);
        int f = k >> CLOG, c = k & ((1 << CLOG) - 1);
        int rg = o >> 4, l15 = o & 15;
        int cs = c >> 5, kseg = (c >> 3) & 3, j = c & 7;   // j aligned to 4
        int NCS = 1 << (CLOG - 5);
        int NK = 64 * NCS;
        int kstep = f * NCS + cs;
        size_t dst = (((size_t)rg * NK + kstep) * 64 + kseg * 16 + l15) * 8 + j;
        const float4 wv = *(const float4*)(W + base);
        *(ushort4*)(Wp + dst) = make_ushort4(f2b(wv.x), f2b(wv.y), f2b(wv.z), f2b(wv.w));
    } else {
        const int base = ((bid - 2560) * 256 + tid) * 4;   // 4 consecutive e
        int b = base >> 12, r = base & 4095, f = r >> 6, e0 = r & 63;
        const float4 xv = *(const float4*)(x + base);
        ushort4 v = make_ushort4(f2b(xv.x), f2b(xv.y), f2b(xv.z), f2b(xv.w));
        unsigned short* xp = x0fp + b * 4096 + f * 64;
        const int hi = e0 >> 4;                            // same for e0..e0+3
        xp[((e0 + 0) & 15) * 4 + hi] = v.x;                // [l15][nt] pack
        xp[((e0 + 1) & 15) * 4 + hi] = v.y;
        xp[((e0 + 2) & 15) * 4 + hi] = v.z;
        xp[((e0 + 3) & 15) * 4 + hi] = v.w;
        x0t[b * 4096 + (e0 + 0) * 64 + f] = v.x;           // [b][e][f]
        x0t[b * 4096 + (e0 + 1) * 64 + f] = v.y;
        x0t[b * 4096 + (e0 + 2) * 64 + f] = v.z;
        x0t[b * 4096 + (e0 + 3) * 64 + f] = v.w;
    }
}

// ---------------- per-layer GEMM kernel ----------------
// grid 512 = 8 rg (16 o-rows, XCD-affine) x 64 sgg (4 samples).
// block = 256 thr = 4 waves; wave w = sample s = sgg*4+w; FULL K per wave
// (16 MFMA/field for CL=128 — R6's proven per-wave shape).
// LDS 48KB -> 3 blocks/CU (independent blocks overlap each other's stalls).
// A: global->LDS 8KB chunks, 2 buffers, 1 syncthreads/chunk. B: bq[NCS][4]
// VGPR-resident + asm-pinned. Scales: packed ds_read_b64, batched per chunk.
template <int CL, bool LAST>
__global__ __launch_bounds__(256, 3) void layer_k(
    const unsigned short* __restrict__ Wp,    // pre-tiled A, rg-sliced
    const unsigned short* __restrict__ Bsrc,  // [b][e][c] rows of CL*2 bytes
    const unsigned short* __restrict__ x0fp,  // [b][f][l15][nt] packed scales
    const float* __restrict__ Wa_l,
    unsigned short* __restrict__ xknext,      // [b][e][o] rows of 256B
    float* __restrict__ ybuf)                 // [256][8] this layer
{
    constexpr int NCS = CL / 32;              // cs granules per field (2 or 4)
    constexpr int NK  = 64 * NCS;             // granules in rg slice
    constexpr int NCH = NK / 8;               // 8-granule (8KB) chunks (16/32)
    constexpr int FPC = 8 / NCS;              // fields per chunk (4 or 2)
    __shared__ char sm[49152];
    char* smA = sm;            // 2 x 8 KB A chunk buffers
    char* smX = sm + 16384;    // 4 x 8 KB per-sample packed scales

    const int bid = blockIdx.x, tid = threadIdx.x;
    const int rg = bid & 7, sgg = bid >> 3;
    const int lane = tid & 63, w = tid >> 6;
    const int s = sgg * 4 + w;
    const int l15 = lane & 15, kseg = lane >> 4;

    // stage 4 samples' packed scales (8 KB each; each wave covers 2KB/sample)
#pragma unroll
    for (int q = 0; q < 4; ++q) {
        const char* src = (const char*)x0fp + (size_t)(sgg * 4 + q) * 8192
                          + w * 2048 + lane * 16;
        char* dst = smX + q * 8192 + w * 2048;
        async16(src, dst);
        async16(src + 1024, dst + 1024);
    }

    const char* Ab = (const char*)Wp + (size_t)rg * NK * 1024;
    auto stage = [&](int ch, int buf) {
        const char* src = Ab + ((size_t)ch * 8 + w * 2) * 1024 + lane * 16;
        char* dst = smA + buf * 8192 + w * 2048;    // wave-uniform dst
        async16(src, dst);
        async16(src + 1024, dst + 1024);
    };
    stage(0, 0);

    // B granules: full K, load once, VGPR-resident
    bf16x8 bq[NCS][4];
    {
        const char* Bb = (const char*)Bsrc + (size_t)s * (CL * 128) + kseg * 16;
#pragma unroll
        for (int cs = 0; cs < NCS; ++cs)
#pragma unroll
            for (int nt = 0; nt < 4; ++nt)
                bq[cs][nt] = *(const bf16x8*)(Bb + (nt * 16 + l15) * (CL * 2) + cs * 64);
    }
    __syncthreads();   // scales + chunk0 complete

    const unsigned short* XS = (const unsigned short*)(smX + w * 8192);
    const f32x4 ZERO = {0.f, 0.f, 0.f, 0.f};
    f32x4 acc[4], accf[4];
#pragma unroll
    for (int nt = 0; nt < 4; ++nt) acc[nt] = ZERO;

    for (int ch = 0; ch < NCH; ++ch) {
        const int cur = ch & 1;
        if (ch + 1 < NCH) stage(ch + 1, cur ^ 1);
        // pin bq (prevents the compiler sinking B loads into the loop)
#pragma unroll
        for (int cs = 0; cs < NCS; ++cs)
            asm volatile("" :: "v"(bq[cs][0]), "v"(bq[cs][1]), "v"(bq[cs][2]), "v"(bq[cs][3]));
        const char* Abuf = smA + cur * 8192 + lane * 16;
        // batch this chunk's fold scales (independent ds_read_b64s)
        uint2 sp[FPC];
#pragma unroll
        for (int fi = 0; fi < FPC; ++fi)
            sp[fi] = *(const uint2*)(XS + (ch * FPC + fi) * 64 + l15 * 4);
#pragma unroll
        for (int fi = 0; fi < FPC; ++fi) {
            bf16x8 a[NCS];
#pragma unroll
            for (int i = 0; i < NCS; ++i)
                a[i] = *(const bf16x8*)(Abuf + (fi * NCS + i) * 1024);
#pragma unroll
            for (int i = 0; i < NCS; ++i)
#pragma unroll
                for (int nt = 0; nt < 4; ++nt)
                    accf[nt] = __builtin_amdgcn_mfma_f32_16x16x32_bf16(
                        a[i], bq[i][nt], (i == 0) ? ZERO : accf[nt], 0, 0, 0);
            const float sv0 = __uint_as_float(sp[fi].x << 16);
            const float sv1 = __uint_as_float(sp[fi].x & 0xffff0000u);
            const float sv2 = __uint_as_float(sp[fi].y << 16);
            const float sv3 = __uint_as_float(sp[fi].y & 0xffff0000u);
            acc[0] += accf[0] * f32x4{sv0, sv0, sv0, sv0};
            acc[1] += accf[1] * f32x4{sv1, sv1, sv1, sv1};
            acc[2] += accf[2] * f32x4{sv2, sv2, sv2, sv2};
            acc[3] += accf[3] * f32x4{sv3, sv3, sv3, sv3};
        }
        __syncthreads();
    }

    // epilogue: relu, y-partial, xknext write (validated mapping; no kg reduce)
    const float4 wa = *(const float4*)(Wa_l + rg * 16 + kseg * 4);
    float ypart = 0.f;
#pragma unroll
    for (int nt = 0; nt < 4; ++nt) {
        f32x4 v = acc[nt];
        v.x = fmaxf(v.x, 0.f); v.y = fmaxf(v.y, 0.f);
        v.z = fmaxf(v.z, 0.f); v.w = fmaxf(v.w, 0.f);
        ypart = fmaf(wa.x, v.x, ypart);
        ypart = fmaf(wa.y, v.y, ypart);
        ypart = fmaf(wa.z, v.z, ypart);
        ypart = fmaf(wa.w, v.w, ypart);
        if (!LAST) {
            unsigned lo = (unsigned)f2b(v.x) | ((unsigned)f2b(v.y) << 16);
            unsigned hi = (unsigned)f2b(v.z) | ((unsigned)f2b(v.w) << 16);
            *(uint2*)((char*)xknext + (size_t)s * 16384 + (nt * 16 + l15) * 256
                      + (rg * 16 + kseg * 4) * 2) = make_uint2(lo, hi);
        }
    }
#pragma unroll
    for (int off = 32; off >= 1; off >>= 1)
        ypart += __shfl_down(ypart, off, 64);
    if (lane == 0) ybuf[s * 8 + rg] = ypart;
}

__global__ void finalize_k(const float* __restrict__ ybuf, float* __restrict__ y) {
    const int b = threadIdx.x;
    float sum = 0.f;
#pragma unroll
    for (int l = 0; l < 3; ++l)
#pragma unroll
        for (int r = 0; r < 8; ++r)
            sum += ybuf[l * 2048 + b * 8 + r];
    y[b] = sum;
}

extern "C" void kernel_launch(void* const* d_in, const int* in_sizes, int n_in,
                              void* d_out, int out_size, void* d_ws, size_t ws_size,
                              hipStream_t stream) {
    const float* x  = (const float*)d_in[0];
    const float* W0 = (const float*)d_in[1];
    const float* W1 = (const float*)d_in[2];
    const float* W2 = (const float*)d_in[3];
    const float* Wa = (const float*)d_in[4];
    float* y = (float*)d_out;

    char* ws = (char*)d_ws;
    unsigned short* Wp0  = (unsigned short*)(ws + 0x000000);   // 1MB (+pad)
    unsigned short* Wp1  = (unsigned short*)(ws + 0x110000);   // 2MB (+pad)
    unsigned short* Wp2  = (unsigned short*)(ws + 0x320000);   // 2MB (+pad)
    unsigned short* x0t  = (unsigned short*)(ws + 0x530000);   // 2MB
    unsigned short* x0fp = (unsigned short*)(ws + 0x730000);   // 2MB
    unsigned short* xkA  = (unsigned short*)(ws + 0x930000);   // 4MB
    unsigned short* xkB  = (unsigned short*)(ws + 0xD30000);   // 4MB
    float*          ybuf = (float*)(ws + 0x1130000);           // 24KB

    hipLaunchKernelGGL(prep_all, dim3(3584), dim3(256), 0, stream,
                       x, W0, W1, W2, x0t, x0fp, Wp0, Wp1, Wp2);

    hipLaunchKernelGGL((layer_k<64, false>), dim3(512), dim3(256), 0, stream,
                       Wp0, x0t, x0fp, Wa + 0, xkA, ybuf + 0);
    hipLaunchKernelGGL((layer_k<128, false>), dim3(512), dim3(256), 0, stream,
                       Wp1, xkA, x0fp, Wa + 128, xkB, ybuf + 2048);
    hipLaunchKernelGGL((layer_k<128, true>), dim3(512), dim3(256), 0, stream,
                       Wp2, xkB, x0fp, Wa + 256, xkA, ybuf + 4096);

    hipLaunchKernelGGL(finalize_k, dim3(1), dim3(256), 0, stream, ybuf, y);
}